// Round 1
// 352.071 us; speedup vs baseline: 1.0814x; 1.0814x over previous
//
#include <hip/hip_runtime.h>
#include <hip/hip_bf16.h>
#include <math.h>

#define D 128
typedef unsigned int uint;
typedef unsigned short ushort;

using bf16x8 = __attribute__((ext_vector_type(8))) short;
using f32x4  = __attribute__((ext_vector_type(4))) float;
using f32x2  = __attribute__((ext_vector_type(2))) float;

static __device__ __forceinline__ ushort f2b(float f) {
    __hip_bfloat16 h = __float2bfloat16(f);
    return __builtin_bit_cast(ushort, h);
}
static __device__ __forceinline__ float blo(uint u) {
    uint v = u << 16;
    return __builtin_bit_cast(float, v);
}
static __device__ __forceinline__ float bhi(uint u) {
    uint v = u & 0xFFFF0000u;
    return __builtin_bit_cast(float, v);
}

// ---------------------------------------------------------------- CSR build
// Single atomic pass: record the slot index per edge so placement is atomic-free.
__global__ void k_degpos(const int* __restrict__ dst, int* __restrict__ deg,
                         int* __restrict__ pos, int E) {
    int e = blockIdx.x * 256 + threadIdx.x;
    if (e < E) pos[e] = atomicAdd(&deg[dst[e]], 1);
}

__global__ void k_scan1(const int* __restrict__ deg, int* __restrict__ rowptr,
                        int* __restrict__ bsum, int nN) {
    __shared__ int s[256];
    int tid = threadIdx.x;
    int i = blockIdx.x * 256 + tid;
    int v = (i < nN) ? deg[i] : 0;
    s[tid] = v;
    __syncthreads();
#pragma unroll
    for (int o = 1; o < 256; o <<= 1) {
        int t = (tid >= o) ? s[tid - o] : 0;
        __syncthreads();
        s[tid] += t;
        __syncthreads();
    }
    if (i < nN) rowptr[i] = s[tid] - v;
    if (tid == 255) bsum[blockIdx.x] = s[255];
}

__global__ void k_scan2(int* __restrict__ bsum, int nb) {
    __shared__ int s[512];
    __shared__ int carry_s;
    int tid = threadIdx.x;
    if (tid == 0) carry_s = 0;
    __syncthreads();
    for (int base = 0; base < nb; base += 512) {
        int i = base + tid;
        int v = (i < nb) ? bsum[i] : 0;
        s[tid] = v;
        __syncthreads();
#pragma unroll
        for (int o = 1; o < 512; o <<= 1) {
            int t = (tid >= o) ? s[tid - o] : 0;
            __syncthreads();
            s[tid] += t;
            __syncthreads();
        }
        int carry = carry_s;
        if (i < nb) bsum[i] = s[tid] - v + carry;
        int total = s[511];
        __syncthreads();
        if (tid == 0) carry_s = carry + total;
        __syncthreads();
    }
}

__global__ void k_scan3(int* __restrict__ rowptr, const int* __restrict__ bsum,
                        int nN, int E) {
    int i = blockIdx.x * 256 + threadIdx.x;
    if (i < nN) rowptr[i] = rowptr[i] + bsum[blockIdx.x];
    if (i == 0) rowptr[nN] = E;
}

// Atomic-free placement: rowptr reads are random but L2-resident (400 KB).
__global__ void k_place2(const int* __restrict__ src, const int* __restrict__ dst,
                         const int* __restrict__ rowptr, const int* __restrict__ pos,
                         int* __restrict__ col, int E) {
    int e = blockIdx.x * 256 + threadIdx.x;
    if (e < E) col[rowptr[dst[e]] + pos[e]] = src[e];
}

// ---------------------------------------------------------------- x fp32 -> bf16 into Abuf cols 128..255
__global__ void k_cast(const float* __restrict__ x, ushort* __restrict__ Abuf, int n4) {
    int i = blockIdx.x * 256 + threadIdx.x;
    if (i >= n4) return;
    float4 v = *(const float4*)(x + (size_t)i * 4);
    int node = i >> 5;
    int coff = (i & 31) * 4;
    ushort4 o;
    o.x = f2b(v.x); o.y = f2b(v.y); o.z = f2b(v.z); o.w = f2b(v.w);
    *(ushort4*)(Abuf + (size_t)node * 256 + 128 + coff) = o;
}

// ---------------------------------------------------------------- all weight prep in one launch
// idx space: [0, 2*128*256) -> Wtg0/Wtg1 ; [2*128*256, +80*128) -> W2tg
__global__ void k_prepw(const float* __restrict__ Wl0, const float* __restrict__ Wr0,
                        const float* __restrict__ Wl1, const float* __restrict__ Wr1,
                        const float* __restrict__ Wl2, const float* __restrict__ Wr2,
                        ushort* __restrict__ Wtg0, ushort* __restrict__ Wtg1,
                        ushort* __restrict__ W2tg) {
    int idx = blockIdx.x * 256 + threadIdx.x;
    if (idx < 2 * 128 * 256) {
        int which = idx >> 15;           // 0 or 1
        int o = idx & 32767;             // j*256 + k
        int j = o >> 8, k = o & 255;
        const float* Wl = which ? Wl1 : Wl0;
        const float* Wr = which ? Wr1 : Wr0;
        float v = (k < 128) ? Wl[j * 128 + k] : Wr[j * 128 + (k - 128)];
        (which ? Wtg1 : Wtg0)[o] = f2b(v);
    } else {
        int o = idx - 2 * 128 * 256;     // j*128 + k, j<80
        if (o >= 80 * 128) return;
        int j = o >> 7, k = o & 127;
        float v = (j < 40) ? Wl2[j * 128 + k] : Wr2[(j - 40) * 128 + k];
        W2tg[o] = f2b(v);
    }
}

// ---------------------------------------------------------------- 128-dim mean-gather, 4 edges/wave-iter, dwordx4 loads
__global__ __launch_bounds__(256) void k_gather128(
    const ushort* __restrict__ feat, ushort* __restrict__ agg,
    const int* __restrict__ rowptr, const int* __restrict__ col, int nN)
{
    int node = blockIdx.x * 4 + (threadIdx.x >> 6);
    if (node >= nN) return;
    int lane = threadIdx.x & 63;
    int g = lane >> 4;          // edge slot 0..3
    int r = lane & 15;          // 16B chunk -> cols 8r..8r+7
    int beg = rowptr[node], end = rowptr[node + 1];
    const char* fb = (const char*)feat;
    const uint rb = (uint)(r << 4);
    float a[8];
#pragma unroll
    for (int i = 0; i < 8; ++i) a[i] = 0.f;

    int j = beg + g;
    for (; j + 4 < end; j += 8) {          // 8 edges per unrolled iter (2 per group)
        int s0 = col[j], s1 = col[j + 4];
        uint4 v0 = *(const uint4*)(fb + (((uint)s0 << 9) + rb));
        uint4 v1 = *(const uint4*)(fb + (((uint)s1 << 9) + rb));
        const uint* p0 = (const uint*)&v0;
        const uint* p1 = (const uint*)&v1;
#pragma unroll
        for (int i = 0; i < 4; ++i) {
            a[2 * i]     += blo(p0[i]) + blo(p1[i]);
            a[2 * i + 1] += bhi(p0[i]) + bhi(p1[i]);
        }
    }
    if (j < end) {
        int s0 = col[j];
        uint4 v0 = *(const uint4*)(fb + (((uint)s0 << 9) + rb));
        const uint* p0 = (const uint*)&v0;
#pragma unroll
        for (int i = 0; i < 4; ++i) {
            a[2 * i]     += blo(p0[i]);
            a[2 * i + 1] += bhi(p0[i]);
        }
    }
#pragma unroll
    for (int i = 0; i < 8; ++i) {
        a[i] += __shfl_xor(a[i], 16);
        a[i] += __shfl_xor(a[i], 32);
    }
    if (g == 0) {
        float inv = 1.0f / (float)max(end - beg, 1);
        uint4 o;
        uint* po = (uint*)&o;
#pragma unroll
        for (int i = 0; i < 4; ++i)
            po[i] = (uint)f2b(a[2 * i] * inv) | ((uint)f2b(a[2 * i + 1] * inv) << 16);
        *(uint4*)(agg + (size_t)node * 256 + r * 8) = o;
    }
}

// ---------------------------------------------------------------- MFMA GEMM
// MODE 0: v += bias[j]; relu; out[m*ostride+j].
// MODE 1: j<40 -> P=out[m*40+j]; j>=40 -> R=out2[m*40+j-40] + bias[j-40].
template<int OUTJ, int KDIM, int SW, int MODE>
__global__ __launch_bounds__(256) void k_gemm_mfma(
    const ushort* __restrict__ A, int astride,
    const ushort* __restrict__ Wt, const float* __restrict__ bias,
    ushort* __restrict__ out, int ostride, ushort* __restrict__ out2, int nN)
{
    constexpr int NT = OUTJ / 16;
    constexpr int KSTEPS = KDIM / 32;
    __shared__ __align__(16) ushort Ws[OUTJ * SW];

    const int tid = threadIdx.x;
    constexpr int CHUNKS = OUTJ * KDIM / 8;
#pragma unroll
    for (int c = tid; c < CHUNKS; c += 256) {
        int row = c / (KDIM / 8);
        int ko  = (c % (KDIM / 8)) * 8;
        *(uint4*)(Ws + row * SW + ko) = *(const uint4*)(Wt + row * KDIM + ko);
    }
    __syncthreads();

    const int l = tid & 63, wv = tid >> 6;
    const int q = l >> 4, r = l & 15;
    const long long m0 = (long long)blockIdx.x * 128 + wv * 32;
    const int mA = (int)min(m0 + r, (long long)(nN - 1));
    const int mB = (int)min(m0 + 16 + r, (long long)(nN - 1));
    const ushort* pa = A + (size_t)mA * astride + q * 8;
    const ushort* pb = A + (size_t)mB * astride + q * 8;

    f32x4 acc[2][NT];
#pragma unroll
    for (int mt = 0; mt < 2; ++mt)
#pragma unroll
        for (int nt = 0; nt < NT; ++nt)
            acc[mt][nt] = (f32x4){0.f, 0.f, 0.f, 0.f};

    bf16x8 a0 = *(const bf16x8*)pa;
    bf16x8 a1 = *(const bf16x8*)pb;
#pragma unroll
    for (int ks = 0; ks < KSTEPS; ++ks) {
        bf16x8 a0n = a0, a1n = a1;
        if (ks + 1 < KSTEPS) {
            a0n = *(const bf16x8*)(pa + (ks + 1) * 32);
            a1n = *(const bf16x8*)(pb + (ks + 1) * 32);
        }
#pragma unroll
        for (int nt = 0; nt < NT; ++nt) {
            bf16x8 b = *(const bf16x8*)(Ws + (nt * 16 + r) * SW + ks * 32 + q * 8);
            acc[0][nt] = __builtin_amdgcn_mfma_f32_16x16x32_bf16(a0, b, acc[0][nt], 0, 0, 0);
            acc[1][nt] = __builtin_amdgcn_mfma_f32_16x16x32_bf16(a1, b, acc[1][nt], 0, 0, 0);
        }
        a0 = a0n; a1 = a1n;
    }

#pragma unroll
    for (int mt = 0; mt < 2; ++mt) {
#pragma unroll
        for (int i = 0; i < 4; ++i) {
            long long m = m0 + mt * 16 + q * 4 + i;
            if (m >= nN) continue;
#pragma unroll
            for (int nt = 0; nt < NT; ++nt) {
                int cc = nt * 16 + r;
                float v = acc[mt][nt][i];
                if (MODE == 0) {
                    v += bias[cc];
                    v = fmaxf(v, 0.f);
                    out[(size_t)m * ostride + cc] = f2b(v);
                } else {
                    if (cc < 40) out[(size_t)m * 40 + cc] = f2b(v);
                    else { v += bias[cc - 40]; out2[(size_t)m * 40 + (cc - 40)] = f2b(v); }
                }
            }
        }
    }
}

// ---------------------------------------------------------------- 40-dim mean-gather + self + log_softmax
// P packed [N,40] bf16; 8 edges/wave-iter, 8 lanes x 16B per edge (r>=5 reads
// spill into next row: finite garbage, masked at softmax).
__global__ __launch_bounds__(256) void k_gather40_lsm(
    const ushort* __restrict__ P, const ushort* __restrict__ R,
    const int* __restrict__ rowptr, const int* __restrict__ col,
    float* __restrict__ out, int nN)
{
    int node = blockIdx.x * 4 + (threadIdx.x >> 6);
    if (node >= nN) return;
    int lane = threadIdx.x & 63;
    int g = lane >> 3;          // edge slot 0..7
    int r = lane & 7;           // 16B chunk -> cols 8r..8r+7 (valid r<5)
    int beg = rowptr[node], end = rowptr[node + 1];
    const char* pbase = (const char*)P;
    const uint rb = (uint)(r << 4);
    f32x2 a2[4];
#pragma unroll
    for (int i = 0; i < 4; ++i) a2[i] = (f32x2){0.f, 0.f};

    for (int j = beg + g; j < end; j += 8) {
        int s = col[j];
        uint off = (((uint)s * 5u) << 4) + rb;   // s*80 + r*16 bytes
        uint4 v = *(const uint4*)(pbase + off);
        const uint* p = (const uint*)&v;
#pragma unroll
        for (int i = 0; i < 4; ++i)
            a2[i] += (f32x2){blo(p[i]), bhi(p[i])};
    }
    float a[8];
#pragma unroll
    for (int i = 0; i < 4; ++i) { a[2 * i] = a2[i].x; a[2 * i + 1] = a2[i].y; }
#pragma unroll
    for (int i = 0; i < 8; ++i) {
        a[i] += __shfl_xor(a[i], 8);
        a[i] += __shfl_xor(a[i], 16);
        a[i] += __shfl_xor(a[i], 32);
    }
    float inv = 1.0f / (float)max(end - beg, 1);
    uint4 rv = *(const uint4*)(R + (size_t)node * 40 + r * 8);
    const uint* pr = (const uint*)&rv;
    float vv[8];
    float mx = -INFINITY;
#pragma unroll
    for (int i = 0; i < 8; ++i) {
        float rc = (i & 1) ? bhi(pr[i >> 1]) : blo(pr[i >> 1]);
        int c = r * 8 + i;
        vv[i] = (c < 40) ? (a[i] * inv + rc) : -INFINITY;
        mx = fmaxf(mx, vv[i]);
    }
    mx = fmaxf(mx, __shfl_xor(mx, 1));
    mx = fmaxf(mx, __shfl_xor(mx, 2));
    mx = fmaxf(mx, __shfl_xor(mx, 4));
    float s = 0.f;
#pragma unroll
    for (int i = 0; i < 8; ++i) {
        int c = r * 8 + i;
        if (c < 40) s += __expf(vv[i] - mx);
    }
    s += __shfl_xor(s, 1);
    s += __shfl_xor(s, 2);
    s += __shfl_xor(s, 4);
    float lse = mx + __logf(s);
    if (g == 0 && r < 5) {
        float4 o0 = make_float4(vv[0] - lse, vv[1] - lse, vv[2] - lse, vv[3] - lse);
        float4 o1 = make_float4(vv[4] - lse, vv[5] - lse, vv[6] - lse, vv[7] - lse);
        *(float4*)(out + (size_t)node * 40 + r * 8)     = o0;
        *(float4*)(out + (size_t)node * 40 + r * 8 + 4) = o1;
    }
}

// ---------------------------------------------------------------- launch
extern "C" void kernel_launch(void* const* d_in, const int* in_sizes, int n_in,
                              void* d_out, int out_size, void* d_ws, size_t ws_size,
                              hipStream_t stream) {
    const float* x   = (const float*)d_in[0];
    const int*   ei  = (const int*)d_in[1];
    const float* Wl0 = (const float*)d_in[2];
    const float* Wr0 = (const float*)d_in[3];
    const float* b0  = (const float*)d_in[4];
    const float* Wl1 = (const float*)d_in[5];
    const float* Wr1 = (const float*)d_in[6];
    const float* b1  = (const float*)d_in[7];
    const float* Wl2 = (const float*)d_in[8];
    const float* Wr2 = (const float*)d_in[9];
    const float* b2  = (const float*)d_in[10];
    const int nN = in_sizes[0] / D;
    const int E  = in_sizes[1] / 2;
    const int* src = ei;
    const int* dst = ei + E;

    char* w = (char*)d_ws;
    auto alloc = [&](size_t bytes) { char* p = w; w += (bytes + 255) & ~(size_t)255; return p; };
    int*    deg    = (int*)   alloc((size_t)nN * 4);
    int*    rowptr = (int*)   alloc((size_t)(nN + 1) * 4);
    int*    bsum   = (int*)   alloc((size_t)((nN + 255) / 256) * 4);
    int*    col    = (int*)   alloc((size_t)E * 4);
    ushort* AbufA  = (ushort*)alloc((size_t)nN * 256 * 2);    // [agg | feat] bf16
    ushort* AbufB  = (ushort*)alloc((size_t)nN * 256 * 2);
    ushort* Wtg0   = (ushort*)alloc((size_t)128 * 256 * 2);
    ushort* Wtg1   = (ushort*)alloc((size_t)128 * 256 * 2);
    ushort* W2tg   = (ushort*)alloc((size_t)80 * 128 * 2);
    // pos aliases AbufB: dead after k_place2, first AbufB write is layer-0 GEMM
    int*    pos    = (int*)AbufB;
    // P/R alias into AbufB (dead after layer-1 GEMM reads it)
    ushort* Pbuf   = AbufB;                    // [N,40] bf16 packed
    ushort* Rbuf   = AbufB + (size_t)nN * 40;  // [N,40] bf16 (8MB offset, 128B-aligned)
    float*  logits = (float*)d_out;

    const int NB        = (nN + 255) / 256;
    const int GATH_BLKS = (nN + 3) / 4;
    const int GEMM_BLKS = (nN + 127) / 128;
    const int PREPW_TOT = 2 * 128 * 256 + 80 * 128;

    // ---- CSR build + casts + weight prep
    hipMemsetAsync(deg, 0, (size_t)nN * 4, stream);
    k_degpos<<<(E + 255) / 256, 256, 0, stream>>>(dst, deg, pos, E);
    k_scan1 <<<NB, 256, 0, stream>>>(deg, rowptr, bsum, nN);
    k_scan2 <<<1, 512, 0, stream>>>(bsum, NB);
    k_scan3 <<<NB, 256, 0, stream>>>(rowptr, bsum, nN, E);
    k_place2<<<(E + 255) / 256, 256, 0, stream>>>(src, dst, rowptr, pos, col, E);
    k_cast  <<<(nN * 32 + 255) / 256, 256, 0, stream>>>(x, AbufA, nN * 32);
    k_prepw <<<(PREPW_TOT + 255) / 256, 256, 0, stream>>>(
        Wl0, Wr0, Wl1, Wr1, Wl2, Wr2, Wtg0, Wtg1, W2tg);

    // ---- layer 0
    k_gather128<<<GATH_BLKS, 256, 0, stream>>>(AbufA + 128, AbufA, rowptr, col, nN);
    k_gemm_mfma<128, 256, 264, 0><<<GEMM_BLKS, 256, 0, stream>>>(
        AbufA, 256, Wtg0, b0, AbufB + 128, 256, nullptr, nN);

    // ---- layer 1
    k_gather128<<<GATH_BLKS, 256, 0, stream>>>(AbufB + 128, AbufB, rowptr, col, nN);
    k_gemm_mfma<128, 256, 264, 0><<<GEMM_BLKS, 256, 0, stream>>>(
        AbufB, 256, Wtg1, b1, AbufA + 128, 256, nullptr, nN);   // h1 -> AbufA cols 128+

    // ---- layer 2: project first, then 40-dim gather + log_softmax
    k_gemm_mfma<80, 128, 136, 1><<<GEMM_BLKS, 256, 0, stream>>>(
        AbufA + 128, 256, W2tg, b2, Pbuf, 40, Rbuf, nN);
    k_gather40_lsm<<<GATH_BLKS, 256, 0, stream>>>(Pbuf, Rbuf, rowptr, col, logits, nN);
}

// Round 2
// 328.444 us; speedup vs baseline: 1.1592x; 1.0719x over previous
//
#include <hip/hip_runtime.h>
#include <hip/hip_bf16.h>
#include <math.h>

#define D 128
typedef unsigned int uint;
typedef unsigned short ushort;

using bf16x8 = __attribute__((ext_vector_type(8))) short;
using f32x4  = __attribute__((ext_vector_type(4))) float;
using f32x2  = __attribute__((ext_vector_type(2))) float;

static __device__ __forceinline__ ushort f2b(float f) {
    __hip_bfloat16 h = __float2bfloat16(f);
    return __builtin_bit_cast(ushort, h);
}
static __device__ __forceinline__ float blo(uint u) {
    uint v = u << 16;
    return __builtin_bit_cast(float, v);
}
static __device__ __forceinline__ float bhi(uint u) {
    uint v = u & 0xFFFF0000u;
    return __builtin_bit_cast(float, v);
}

// ---------------------------------------------------------------- CSR build
// Single atomic pass: record the slot index per edge so placement is atomic-free.
__global__ void k_degpos(const int* __restrict__ dst, int* __restrict__ deg,
                         int* __restrict__ pos, int E) {
    int e = blockIdx.x * 256 + threadIdx.x;
    if (e < E) pos[e] = atomicAdd(&deg[dst[e]], 1);
}

__global__ void k_scan1(const int* __restrict__ deg, int* __restrict__ rowptr,
                        int* __restrict__ bsum, int nN) {
    __shared__ int s[256];
    int tid = threadIdx.x;
    int i = blockIdx.x * 256 + tid;
    int v = (i < nN) ? deg[i] : 0;
    s[tid] = v;
    __syncthreads();
#pragma unroll
    for (int o = 1; o < 256; o <<= 1) {
        int t = (tid >= o) ? s[tid - o] : 0;
        __syncthreads();
        s[tid] += t;
        __syncthreads();
    }
    if (i < nN) rowptr[i] = s[tid] - v;
    if (tid == 255) bsum[blockIdx.x] = s[255];
}

__global__ void k_scan2(int* __restrict__ bsum, int nb) {
    __shared__ int s[512];
    __shared__ int carry_s;
    int tid = threadIdx.x;
    if (tid == 0) carry_s = 0;
    __syncthreads();
    for (int base = 0; base < nb; base += 512) {
        int i = base + tid;
        int v = (i < nb) ? bsum[i] : 0;
        s[tid] = v;
        __syncthreads();
#pragma unroll
        for (int o = 1; o < 512; o <<= 1) {
            int t = (tid >= o) ? s[tid - o] : 0;
            __syncthreads();
            s[tid] += t;
            __syncthreads();
        }
        int carry = carry_s;
        if (i < nb) bsum[i] = s[tid] - v + carry;
        int total = s[511];
        __syncthreads();
        if (tid == 0) carry_s = carry + total;
        __syncthreads();
    }
}

__global__ void k_scan3(int* __restrict__ rowptr, const int* __restrict__ bsum,
                        int nN, int E) {
    int i = blockIdx.x * 256 + threadIdx.x;
    if (i < nN) rowptr[i] = rowptr[i] + bsum[blockIdx.x];
    if (i == 0) rowptr[nN] = E;
}

// Atomic-free placement: rowptr reads are random but L2-resident (400 KB).
__global__ void k_place2(const int* __restrict__ src, const int* __restrict__ dst,
                         const int* __restrict__ rowptr, const int* __restrict__ pos,
                         int* __restrict__ col, int E) {
    int e = blockIdx.x * 256 + threadIdx.x;
    if (e < E) col[rowptr[dst[e]] + pos[e]] = src[e];
}

// ---------------------------------------------------------------- x fp32 -> bf16 into Abuf cols 128..255
__global__ void k_cast(const float* __restrict__ x, ushort* __restrict__ Abuf, int n4) {
    int i = blockIdx.x * 256 + threadIdx.x;
    if (i >= n4) return;
    float4 v = *(const float4*)(x + (size_t)i * 4);
    int node = i >> 5;
    int coff = (i & 31) * 4;
    ushort4 o;
    o.x = f2b(v.x); o.y = f2b(v.y); o.z = f2b(v.z); o.w = f2b(v.w);
    *(ushort4*)(Abuf + (size_t)node * 256 + 128 + coff) = o;
}

// ---------------------------------------------------------------- all weight prep in one launch
// idx space: [0, 2*128*256) -> Wtg0/Wtg1 ; [2*128*256, +80*128) -> W2tg
__global__ void k_prepw(const float* __restrict__ Wl0, const float* __restrict__ Wr0,
                        const float* __restrict__ Wl1, const float* __restrict__ Wr1,
                        const float* __restrict__ Wl2, const float* __restrict__ Wr2,
                        ushort* __restrict__ Wtg0, ushort* __restrict__ Wtg1,
                        ushort* __restrict__ W2tg) {
    int idx = blockIdx.x * 256 + threadIdx.x;
    if (idx < 2 * 128 * 256) {
        int which = idx >> 15;           // 0 or 1
        int o = idx & 32767;             // j*256 + k
        int j = o >> 8, k = o & 255;
        const float* Wl = which ? Wl1 : Wl0;
        const float* Wr = which ? Wr1 : Wr0;
        float v = (k < 128) ? Wl[j * 128 + k] : Wr[j * 128 + (k - 128)];
        (which ? Wtg1 : Wtg0)[o] = f2b(v);
    } else {
        int o = idx - 2 * 128 * 256;     // j*128 + k, j<80
        if (o >= 80 * 128) return;
        int j = o >> 7, k = o & 127;
        float v = (j < 40) ? Wl2[j * 128 + k] : Wr2[(j - 40) * 128 + k];
        W2tg[o] = f2b(v);
    }
}

// ---------------------------------------------------------------- 128-dim mean-gather
// 2 nodes per wave: h=lane>>5 picks node, 2 edge slots x 16 chunks of 16B.
__global__ __launch_bounds__(256) void k_gather128(
    const ushort* __restrict__ feat, ushort* __restrict__ agg,
    const int* __restrict__ rowptr, const int* __restrict__ col, int nN)
{
    int tid = threadIdx.x;
    int lane = tid & 63;
    int h = lane >> 5;
    int node = blockIdx.x * 8 + ((tid >> 6) << 1) + h;
    if (node >= nN) return;
    int g = (lane >> 4) & 1;    // edge slot 0..1
    int r = lane & 15;          // 16B chunk -> cols 8r..8r+7
    int beg = rowptr[node], end = rowptr[node + 1];
    const char* fb = (const char*)feat;
    const uint rb = (uint)(r << 4);
    float a[8];
#pragma unroll
    for (int i = 0; i < 8; ++i) a[i] = 0.f;

    int j = beg + g;
    for (; j + 2 < end; j += 4) {          // 4 edges/node per unrolled iter
        int s0 = col[j], s1 = col[j + 2];
        uint4 v0 = *(const uint4*)(fb + (((uint)s0 << 9) + rb));
        uint4 v1 = *(const uint4*)(fb + (((uint)s1 << 9) + rb));
        const uint* p0 = (const uint*)&v0;
        const uint* p1 = (const uint*)&v1;
#pragma unroll
        for (int i = 0; i < 4; ++i) {
            a[2 * i]     += blo(p0[i]) + blo(p1[i]);
            a[2 * i + 1] += bhi(p0[i]) + bhi(p1[i]);
        }
    }
    if (j < end) {
        int s0 = col[j];
        uint4 v0 = *(const uint4*)(fb + (((uint)s0 << 9) + rb));
        const uint* p0 = (const uint*)&v0;
#pragma unroll
        for (int i = 0; i < 4; ++i) {
            a[2 * i]     += blo(p0[i]);
            a[2 * i + 1] += bhi(p0[i]);
        }
    }
#pragma unroll
    for (int i = 0; i < 8; ++i)
        a[i] += __shfl_xor(a[i], 16);      // reduce across the 2 slots
    if (g == 0) {
        float inv = 1.0f / (float)max(end - beg, 1);
        uint4 o;
        uint* po = (uint*)&o;
#pragma unroll
        for (int i = 0; i < 4; ++i)
            po[i] = (uint)f2b(a[2 * i] * inv) | ((uint)f2b(a[2 * i + 1] * inv) << 16);
        *(uint4*)(agg + (size_t)node * 256 + r * 8) = o;
    }
}

// ---------------------------------------------------------------- MFMA GEMM
// MODE 0: v += bias[j]; relu; out[m*ostride+j].
// MODE 1: j<40 -> P=out[m*40+j]; j>=40 -> R=out2[m*40+j-40] + bias[j-40].
template<int OUTJ, int KDIM, int SW, int MODE>
__global__ __launch_bounds__(256) void k_gemm_mfma(
    const ushort* __restrict__ A, int astride,
    const ushort* __restrict__ Wt, const float* __restrict__ bias,
    ushort* __restrict__ out, int ostride, ushort* __restrict__ out2, int nN)
{
    constexpr int NT = OUTJ / 16;
    constexpr int KSTEPS = KDIM / 32;
    __shared__ __align__(16) ushort Ws[OUTJ * SW];

    const int tid = threadIdx.x;
    constexpr int CHUNKS = OUTJ * KDIM / 8;
#pragma unroll
    for (int c = tid; c < CHUNKS; c += 256) {
        int row = c / (KDIM / 8);
        int ko  = (c % (KDIM / 8)) * 8;
        *(uint4*)(Ws + row * SW + ko) = *(const uint4*)(Wt + row * KDIM + ko);
    }
    __syncthreads();

    const int l = tid & 63, wv = tid >> 6;
    const int q = l >> 4, r = l & 15;
    const long long m0 = (long long)blockIdx.x * 128 + wv * 32;
    const int mA = (int)min(m0 + r, (long long)(nN - 1));
    const int mB = (int)min(m0 + 16 + r, (long long)(nN - 1));
    const ushort* pa = A + (size_t)mA * astride + q * 8;
    const ushort* pb = A + (size_t)mB * astride + q * 8;

    f32x4 acc[2][NT];
#pragma unroll
    for (int mt = 0; mt < 2; ++mt)
#pragma unroll
        for (int nt = 0; nt < NT; ++nt)
            acc[mt][nt] = (f32x4){0.f, 0.f, 0.f, 0.f};

    bf16x8 a0 = *(const bf16x8*)pa;
    bf16x8 a1 = *(const bf16x8*)pb;
#pragma unroll
    for (int ks = 0; ks < KSTEPS; ++ks) {
        bf16x8 a0n = a0, a1n = a1;
        if (ks + 1 < KSTEPS) {
            a0n = *(const bf16x8*)(pa + (ks + 1) * 32);
            a1n = *(const bf16x8*)(pb + (ks + 1) * 32);
        }
#pragma unroll
        for (int nt = 0; nt < NT; ++nt) {
            bf16x8 b = *(const bf16x8*)(Ws + (nt * 16 + r) * SW + ks * 32 + q * 8);
            acc[0][nt] = __builtin_amdgcn_mfma_f32_16x16x32_bf16(a0, b, acc[0][nt], 0, 0, 0);
            acc[1][nt] = __builtin_amdgcn_mfma_f32_16x16x32_bf16(a1, b, acc[1][nt], 0, 0, 0);
        }
        a0 = a0n; a1 = a1n;
    }

#pragma unroll
    for (int mt = 0; mt < 2; ++mt) {
#pragma unroll
        for (int i = 0; i < 4; ++i) {
            long long m = m0 + mt * 16 + q * 4 + i;
            if (m >= nN) continue;
#pragma unroll
            for (int nt = 0; nt < NT; ++nt) {
                int cc = nt * 16 + r;
                float v = acc[mt][nt][i];
                if (MODE == 0) {
                    v += bias[cc];
                    v = fmaxf(v, 0.f);
                    out[(size_t)m * ostride + cc] = f2b(v);
                } else {
                    if (cc < 40) out[(size_t)m * 40 + cc] = f2b(v);
                    else { v += bias[cc - 40]; out2[(size_t)m * 40 + (cc - 40)] = f2b(v); }
                }
            }
        }
    }
}

// ---------------------------------------------------------------- 40-dim mean-gather + self + log_softmax
// 2 nodes per wave: h=lane>>5, 4 edge slots x 8 chunks of 16B (r>=5 reads spill
// into next row: finite garbage, masked at softmax).
__global__ __launch_bounds__(256) void k_gather40_lsm(
    const ushort* __restrict__ P, const ushort* __restrict__ R,
    const int* __restrict__ rowptr, const int* __restrict__ col,
    float* __restrict__ out, int nN)
{
    int tid = threadIdx.x;
    int lane = tid & 63;
    int h = lane >> 5;
    int node = blockIdx.x * 8 + ((tid >> 6) << 1) + h;
    if (node >= nN) return;
    int g = (lane >> 3) & 3;    // edge slot 0..3
    int r = lane & 7;           // 16B chunk -> cols 8r..8r+7 (valid r<5)
    int beg = rowptr[node], end = rowptr[node + 1];
    const char* pbase = (const char*)P;
    const uint rb = (uint)(r << 4);
    f32x2 a2[4];
#pragma unroll
    for (int i = 0; i < 4; ++i) a2[i] = (f32x2){0.f, 0.f};

    int j = beg + g;
    for (; j + 4 < end; j += 8) {          // 8 edges/node per unrolled iter
        int s0 = col[j], s1 = col[j + 4];
        uint4 v0 = *(const uint4*)(pbase + ((((uint)s0 * 5u) << 4) + rb));
        uint4 v1 = *(const uint4*)(pbase + ((((uint)s1 * 5u) << 4) + rb));
        const uint* p0 = (const uint*)&v0;
        const uint* p1 = (const uint*)&v1;
#pragma unroll
        for (int i = 0; i < 4; ++i)
            a2[i] += (f32x2){blo(p0[i]) + blo(p1[i]), bhi(p0[i]) + bhi(p1[i])};
    }
    if (j < end) {
        int s0 = col[j];
        uint4 v0 = *(const uint4*)(pbase + ((((uint)s0 * 5u) << 4) + rb));
        const uint* p0 = (const uint*)&v0;
#pragma unroll
        for (int i = 0; i < 4; ++i)
            a2[i] += (f32x2){blo(p0[i]), bhi(p0[i])};
    }
    float a[8];
#pragma unroll
    for (int i = 0; i < 4; ++i) { a[2 * i] = a2[i].x; a[2 * i + 1] = a2[i].y; }
#pragma unroll
    for (int i = 0; i < 8; ++i) {
        a[i] += __shfl_xor(a[i], 8);       // reduce across the 4 slots
        a[i] += __shfl_xor(a[i], 16);
    }
    float inv = 1.0f / (float)max(end - beg, 1);
    uint4 rv = *(const uint4*)(R + (size_t)node * 40 + r * 8);
    const uint* pr = (const uint*)&rv;
    float vv[8];
    float mx = -INFINITY;
#pragma unroll
    for (int i = 0; i < 8; ++i) {
        float rc = (i & 1) ? bhi(pr[i >> 1]) : blo(pr[i >> 1]);
        int c = r * 8 + i;
        vv[i] = (c < 40) ? (a[i] * inv + rc) : -INFINITY;
        mx = fmaxf(mx, vv[i]);
    }
    mx = fmaxf(mx, __shfl_xor(mx, 1));
    mx = fmaxf(mx, __shfl_xor(mx, 2));
    mx = fmaxf(mx, __shfl_xor(mx, 4));
    float s = 0.f;
#pragma unroll
    for (int i = 0; i < 8; ++i) {
        int c = r * 8 + i;
        if (c < 40) s += __expf(vv[i] - mx);
    }
    s += __shfl_xor(s, 1);
    s += __shfl_xor(s, 2);
    s += __shfl_xor(s, 4);
    float lse = mx + __logf(s);
    if (g == 0 && r < 5) {
        float4 o0 = make_float4(vv[0] - lse, vv[1] - lse, vv[2] - lse, vv[3] - lse);
        float4 o1 = make_float4(vv[4] - lse, vv[5] - lse, vv[6] - lse, vv[7] - lse);
        *(float4*)(out + (size_t)node * 40 + r * 8)     = o0;
        *(float4*)(out + (size_t)node * 40 + r * 8 + 4) = o1;
    }
}

// ---------------------------------------------------------------- launch
extern "C" void kernel_launch(void* const* d_in, const int* in_sizes, int n_in,
                              void* d_out, int out_size, void* d_ws, size_t ws_size,
                              hipStream_t stream) {
    const float* x   = (const float*)d_in[0];
    const int*   ei  = (const int*)d_in[1];
    const float* Wl0 = (const float*)d_in[2];
    const float* Wr0 = (const float*)d_in[3];
    const float* b0  = (const float*)d_in[4];
    const float* Wl1 = (const float*)d_in[5];
    const float* Wr1 = (const float*)d_in[6];
    const float* b1  = (const float*)d_in[7];
    const float* Wl2 = (const float*)d_in[8];
    const float* Wr2 = (const float*)d_in[9];
    const float* b2  = (const float*)d_in[10];
    const int nN = in_sizes[0] / D;
    const int E  = in_sizes[1] / 2;
    const int* src = ei;
    const int* dst = ei + E;

    char* w = (char*)d_ws;
    auto alloc = [&](size_t bytes) { char* p = w; w += (bytes + 255) & ~(size_t)255; return p; };
    int*    deg    = (int*)   alloc((size_t)nN * 4);
    int*    rowptr = (int*)   alloc((size_t)(nN + 1) * 4);
    int*    bsum   = (int*)   alloc((size_t)((nN + 255) / 256) * 4);
    int*    col    = (int*)   alloc((size_t)E * 4);
    ushort* AbufA  = (ushort*)alloc((size_t)nN * 256 * 2);    // [agg | feat] bf16
    ushort* AbufB  = (ushort*)alloc((size_t)nN * 256 * 2);
    ushort* Wtg0   = (ushort*)alloc((size_t)128 * 256 * 2);
    ushort* Wtg1   = (ushort*)alloc((size_t)128 * 256 * 2);
    ushort* W2tg   = (ushort*)alloc((size_t)80 * 128 * 2);
    // pos aliases AbufB: dead after k_place2, first AbufB write is layer-0 GEMM
    int*    pos    = (int*)AbufB;
    // P/R alias into AbufB (dead after layer-1 GEMM reads it)
    ushort* Pbuf   = AbufB;                    // [N,40] bf16 packed
    ushort* Rbuf   = AbufB + (size_t)nN * 40;  // [N,40] bf16 (8MB offset, 128B-aligned)
    float*  logits = (float*)d_out;

    const int NB        = (nN + 255) / 256;
    const int GATH_BLKS = (nN + 7) / 8;        // 8 nodes per block (2 per wave)
    const int GEMM_BLKS = (nN + 127) / 128;
    const int PREPW_TOT = 2 * 128 * 256 + 80 * 128;

    // ---- CSR build + casts + weight prep
    hipMemsetAsync(deg, 0, (size_t)nN * 4, stream);
    k_degpos<<<(E + 255) / 256, 256, 0, stream>>>(dst, deg, pos, E);
    k_scan1 <<<NB, 256, 0, stream>>>(deg, rowptr, bsum, nN);
    k_scan2 <<<1, 512, 0, stream>>>(bsum, NB);
    k_scan3 <<<NB, 256, 0, stream>>>(rowptr, bsum, nN, E);
    k_place2<<<(E + 255) / 256, 256, 0, stream>>>(src, dst, rowptr, pos, col, E);
    k_cast  <<<(nN * 32 + 255) / 256, 256, 0, stream>>>(x, AbufA, nN * 32);
    k_prepw <<<(PREPW_TOT + 255) / 256, 256, 0, stream>>>(
        Wl0, Wr0, Wl1, Wr1, Wl2, Wr2, Wtg0, Wtg1, W2tg);

    // ---- layer 0
    k_gather128<<<GATH_BLKS, 256, 0, stream>>>(AbufA + 128, AbufA, rowptr, col, nN);
    k_gemm_mfma<128, 256, 264, 0><<<GEMM_BLKS, 256, 0, stream>>>(
        AbufA, 256, Wtg0, b0, AbufB + 128, 256, nullptr, nN);

    // ---- layer 1
    k_gather128<<<GATH_BLKS, 256, 0, stream>>>(AbufB + 128, AbufB, rowptr, col, nN);
    k_gemm_mfma<128, 256, 264, 0><<<GEMM_BLKS, 256, 0, stream>>>(
        AbufB, 256, Wtg1, b1, AbufA + 128, 256, nullptr, nN);   // h1 -> AbufA cols 128+

    // ---- layer 2: project first, then 40-dim gather + log_softmax
    k_gemm_mfma<80, 128, 136, 1><<<GEMM_BLKS, 256, 0, stream>>>(
        AbufA + 128, 256, W2tg, b2, Pbuf, 40, Rbuf, nN);
    k_gather40_lsm<<<GATH_BLKS, 256, 0, stream>>>(Pbuf, Rbuf, rowptr, col, logits, nN);
}

// Round 3
// 321.593 us; speedup vs baseline: 1.1839x; 1.0213x over previous
//
#include <hip/hip_runtime.h>
#include <hip/hip_bf16.h>
#include <math.h>

#define D 128
typedef unsigned int uint;
typedef unsigned short ushort;

using bf16x8 = __attribute__((ext_vector_type(8))) short;
using f32x4  = __attribute__((ext_vector_type(4))) float;
using f32x2  = __attribute__((ext_vector_type(2))) float;

static __device__ __forceinline__ ushort f2b(float f) {
    __hip_bfloat16 h = __float2bfloat16(f);
    return __builtin_bit_cast(ushort, h);
}
static __device__ __forceinline__ float blo(uint u) {
    uint v = u << 16;
    return __builtin_bit_cast(float, v);
}
static __device__ __forceinline__ float bhi(uint u) {
    uint v = u & 0xFFFF0000u;
    return __builtin_bit_cast(float, v);
}

// ---------------------------------------------------------------- fused prologue
// Per-thread fusion of three independent jobs: the atomic's round-trip latency
// (degpos) overlaps the BW-bound cast work in the same wave.
__global__ __launch_bounds__(256) void k_prep(
    const int* __restrict__ dst, int* __restrict__ deg, int* __restrict__ pos, int E,
    const float* __restrict__ x, ushort* __restrict__ Abuf, int n4,
    const float* __restrict__ Wl0, const float* __restrict__ Wr0,
    const float* __restrict__ Wl1, const float* __restrict__ Wr1,
    const float* __restrict__ Wl2, const float* __restrict__ Wr2,
    ushort* __restrict__ Wtg0, ushort* __restrict__ Wtg1,
    ushort* __restrict__ W2tg)
{
    int i = blockIdx.x * 256 + threadIdx.x;
    int p = -1;
    if (i < E) p = atomicAdd(&deg[dst[i]], 1);   // issue early; latency hidden below
    if (i < n4) {
        float4 v = *(const float4*)(x + (size_t)i * 4);
        int node = i >> 5;
        int coff = (i & 31) * 4;
        ushort4 o;
        o.x = f2b(v.x); o.y = f2b(v.y); o.z = f2b(v.z); o.w = f2b(v.w);
        *(ushort4*)(Abuf + (size_t)node * 256 + 128 + coff) = o;
    }
    if (i < 2 * 128 * 256) {
        int which = i >> 15;             // 0 or 1
        int o = i & 32767;               // j*256 + k
        int j = o >> 8, k = o & 255;
        const float* Wl = which ? Wl1 : Wl0;
        const float* Wr = which ? Wr1 : Wr0;
        float v = (k < 128) ? Wl[j * 128 + k] : Wr[j * 128 + (k - 128)];
        (which ? Wtg1 : Wtg0)[o] = f2b(v);
    } else if (i < 2 * 128 * 256 + 80 * 128) {
        int o = i - 2 * 128 * 256;       // j*128 + k, j<80
        int j = o >> 7, k = o & 127;
        float v = (j < 40) ? Wl2[j * 128 + k] : Wr2[(j - 40) * 128 + k];
        W2tg[o] = f2b(v);
    }
    if (i < E) pos[i] = p;
}

__global__ void k_scan1(const int* __restrict__ deg, int* __restrict__ rowptr,
                        int* __restrict__ bsum, int nN) {
    __shared__ int s[256];
    int tid = threadIdx.x;
    int i = blockIdx.x * 256 + tid;
    int v = (i < nN) ? deg[i] : 0;
    s[tid] = v;
    __syncthreads();
#pragma unroll
    for (int o = 1; o < 256; o <<= 1) {
        int t = (tid >= o) ? s[tid - o] : 0;
        __syncthreads();
        s[tid] += t;
        __syncthreads();
    }
    if (i < nN) rowptr[i] = s[tid] - v;
    if (tid == 255) bsum[blockIdx.x] = s[255];
}

__global__ void k_scan2(int* __restrict__ bsum, int nb) {
    __shared__ int s[512];
    __shared__ int carry_s;
    int tid = threadIdx.x;
    if (tid == 0) carry_s = 0;
    __syncthreads();
    for (int base = 0; base < nb; base += 512) {
        int i = base + tid;
        int v = (i < nb) ? bsum[i] : 0;
        s[tid] = v;
        __syncthreads();
#pragma unroll
        for (int o = 1; o < 512; o <<= 1) {
            int t = (tid >= o) ? s[tid - o] : 0;
            __syncthreads();
            s[tid] += t;
            __syncthreads();
        }
        int carry = carry_s;
        if (i < nb) bsum[i] = s[tid] - v + carry;
        int total = s[511];
        __syncthreads();
        if (tid == 0) carry_s = carry + total;
        __syncthreads();
    }
}

__global__ void k_scan3(int* __restrict__ rowptr, const int* __restrict__ bsum,
                        int nN, int E) {
    int i = blockIdx.x * 256 + threadIdx.x;
    if (i < nN) rowptr[i] = rowptr[i] + bsum[blockIdx.x];
    if (i == 0) rowptr[nN] = E;
}

// Atomic-free placement: rowptr reads are random but L2-resident (400 KB).
__global__ void k_place2(const int* __restrict__ src, const int* __restrict__ dst,
                         const int* __restrict__ rowptr, const int* __restrict__ pos,
                         int* __restrict__ col, int E) {
    int e = blockIdx.x * 256 + threadIdx.x;
    if (e < E) col[rowptr[dst[e]] + pos[e]] = src[e];
}

// ---------------------------------------------------------------- 128-dim mean-gather
// 2 nodes per wave: h=lane>>5 picks node, 2 edge slots x 16 chunks of 16B.
__global__ __launch_bounds__(256) void k_gather128(
    const ushort* __restrict__ feat, ushort* __restrict__ agg,
    const int* __restrict__ rowptr, const int* __restrict__ col, int nN)
{
    int tid = threadIdx.x;
    int lane = tid & 63;
    int h = lane >> 5;
    int node = blockIdx.x * 8 + ((tid >> 6) << 1) + h;
    if (node >= nN) return;
    int g = (lane >> 4) & 1;    // edge slot 0..1
    int r = lane & 15;          // 16B chunk -> cols 8r..8r+7
    int beg = rowptr[node], end = rowptr[node + 1];
    const char* fb = (const char*)feat;
    const uint rb = (uint)(r << 4);
    float a[8];
#pragma unroll
    for (int i = 0; i < 8; ++i) a[i] = 0.f;

    int j = beg + g;
    for (; j + 2 < end; j += 4) {          // 4 edges/node per unrolled iter
        int s0 = col[j], s1 = col[j + 2];
        uint4 v0 = *(const uint4*)(fb + (((uint)s0 << 9) + rb));
        uint4 v1 = *(const uint4*)(fb + (((uint)s1 << 9) + rb));
        const uint* p0 = (const uint*)&v0;
        const uint* p1 = (const uint*)&v1;
#pragma unroll
        for (int i = 0; i < 4; ++i) {
            a[2 * i]     += blo(p0[i]) + blo(p1[i]);
            a[2 * i + 1] += bhi(p0[i]) + bhi(p1[i]);
        }
    }
    if (j < end) {
        int s0 = col[j];
        uint4 v0 = *(const uint4*)(fb + (((uint)s0 << 9) + rb));
        const uint* p0 = (const uint*)&v0;
#pragma unroll
        for (int i = 0; i < 4; ++i) {
            a[2 * i]     += blo(p0[i]);
            a[2 * i + 1] += bhi(p0[i]);
        }
    }
#pragma unroll
    for (int i = 0; i < 8; ++i)
        a[i] += __shfl_xor(a[i], 16);      // reduce across the 2 slots
    if (g == 0) {
        float inv = 1.0f / (float)max(end - beg, 1);
        uint4 o;
        uint* po = (uint*)&o;
#pragma unroll
        for (int i = 0; i < 4; ++i)
            po[i] = (uint)f2b(a[2 * i] * inv) | ((uint)f2b(a[2 * i + 1] * inv) << 16);
        *(uint4*)(agg + (size_t)node * 256 + r * 8) = o;
    }
}

// ---------------------------------------------------------------- MFMA GEMM
// MODE 0: v += bias[j]; relu; out[m*ostride+j].
// MODE 1: j<40 -> P=out[m*40+j]; j>=40 -> R=out2[m*40+j-40] + bias[j-40].
template<int OUTJ, int KDIM, int SW, int MODE>
__global__ __launch_bounds__(256) void k_gemm_mfma(
    const ushort* __restrict__ A, int astride,
    const ushort* __restrict__ Wt, const float* __restrict__ bias,
    ushort* __restrict__ out, int ostride, ushort* __restrict__ out2, int nN)
{
    constexpr int NT = OUTJ / 16;
    constexpr int KSTEPS = KDIM / 32;
    __shared__ __align__(16) ushort Ws[OUTJ * SW];

    const int tid = threadIdx.x;
    constexpr int CHUNKS = OUTJ * KDIM / 8;
#pragma unroll
    for (int c = tid; c < CHUNKS; c += 256) {
        int row = c / (KDIM / 8);
        int ko  = (c % (KDIM / 8)) * 8;
        *(uint4*)(Ws + row * SW + ko) = *(const uint4*)(Wt + row * KDIM + ko);
    }
    __syncthreads();

    const int l = tid & 63, wv = tid >> 6;
    const int q = l >> 4, r = l & 15;
    const long long m0 = (long long)blockIdx.x * 128 + wv * 32;
    const int mA = (int)min(m0 + r, (long long)(nN - 1));
    const int mB = (int)min(m0 + 16 + r, (long long)(nN - 1));
    const ushort* pa = A + (size_t)mA * astride + q * 8;
    const ushort* pb = A + (size_t)mB * astride + q * 8;

    f32x4 acc[2][NT];
#pragma unroll
    for (int mt = 0; mt < 2; ++mt)
#pragma unroll
        for (int nt = 0; nt < NT; ++nt)
            acc[mt][nt] = (f32x4){0.f, 0.f, 0.f, 0.f};

    bf16x8 a0 = *(const bf16x8*)pa;
    bf16x8 a1 = *(const bf16x8*)pb;
#pragma unroll
    for (int ks = 0; ks < KSTEPS; ++ks) {
        bf16x8 a0n = a0, a1n = a1;
        if (ks + 1 < KSTEPS) {
            a0n = *(const bf16x8*)(pa + (ks + 1) * 32);
            a1n = *(const bf16x8*)(pb + (ks + 1) * 32);
        }
#pragma unroll
        for (int nt = 0; nt < NT; ++nt) {
            bf16x8 b = *(const bf16x8*)(Ws + (nt * 16 + r) * SW + ks * 32 + q * 8);
            acc[0][nt] = __builtin_amdgcn_mfma_f32_16x16x32_bf16(a0, b, acc[0][nt], 0, 0, 0);
            acc[1][nt] = __builtin_amdgcn_mfma_f32_16x16x32_bf16(a1, b, acc[1][nt], 0, 0, 0);
        }
        a0 = a0n; a1 = a1n;
    }

#pragma unroll
    for (int mt = 0; mt < 2; ++mt) {
#pragma unroll
        for (int i = 0; i < 4; ++i) {
            long long m = m0 + mt * 16 + q * 4 + i;
            if (m >= nN) continue;
#pragma unroll
            for (int nt = 0; nt < NT; ++nt) {
                int cc = nt * 16 + r;
                float v = acc[mt][nt][i];
                if (MODE == 0) {
                    v += bias[cc];
                    v = fmaxf(v, 0.f);
                    out[(size_t)m * ostride + cc] = f2b(v);
                } else {
                    if (cc < 40) out[(size_t)m * 40 + cc] = f2b(v);
                    else { v += bias[cc - 40]; out2[(size_t)m * 40 + (cc - 40)] = f2b(v); }
                }
            }
        }
    }
}

// ---------------------------------------------------------------- 40-dim mean-gather + self + log_softmax
// 4 nodes per wave: h=lane>>4, 2 edge slots x 8 chunks of 16B (r>=5 reads spill
// into next row: finite garbage, masked at softmax).
__global__ __launch_bounds__(256) void k_gather40_lsm(
    const ushort* __restrict__ P, const ushort* __restrict__ R,
    const int* __restrict__ rowptr, const int* __restrict__ col,
    float* __restrict__ out, int nN)
{
    int tid = threadIdx.x;
    int lane = tid & 63;
    int h = lane >> 4;          // node sub 0..3
    int node = blockIdx.x * 16 + ((tid >> 6) << 2) + h;
    if (node >= nN) return;
    int g = (lane >> 3) & 1;    // edge slot 0..1
    int r = lane & 7;           // 16B chunk -> cols 8r..8r+7 (valid r<5)
    int beg = rowptr[node], end = rowptr[node + 1];
    const char* pbase = (const char*)P;
    const uint rb = (uint)(r << 4);
    f32x2 a2[4];
#pragma unroll
    for (int i = 0; i < 4; ++i) a2[i] = (f32x2){0.f, 0.f};

    int j = beg + g;
    for (; j + 2 < end; j += 4) {          // 4 edges/node per unrolled iter
        int s0 = col[j], s1 = col[j + 2];
        uint4 v0 = *(const uint4*)(pbase + ((((uint)s0 * 5u) << 4) + rb));
        uint4 v1 = *(const uint4*)(pbase + ((((uint)s1 * 5u) << 4) + rb));
        const uint* p0 = (const uint*)&v0;
        const uint* p1 = (const uint*)&v1;
#pragma unroll
        for (int i = 0; i < 4; ++i)
            a2[i] += (f32x2){blo(p0[i]) + blo(p1[i]), bhi(p0[i]) + bhi(p1[i])};
    }
    if (j < end) {
        int s0 = col[j];
        uint4 v0 = *(const uint4*)(pbase + ((((uint)s0 * 5u) << 4) + rb));
        const uint* p0 = (const uint*)&v0;
#pragma unroll
        for (int i = 0; i < 4; ++i)
            a2[i] += (f32x2){blo(p0[i]), bhi(p0[i])};
    }
    float a[8];
#pragma unroll
    for (int i = 0; i < 4; ++i) { a[2 * i] = a2[i].x; a[2 * i + 1] = a2[i].y; }
#pragma unroll
    for (int i = 0; i < 8; ++i)
        a[i] += __shfl_xor(a[i], 8);       // reduce across the 2 slots
    float inv = 1.0f / (float)max(end - beg, 1);
    uint4 rv = *(const uint4*)(R + (size_t)node * 40 + r * 8);
    const uint* pr = (const uint*)&rv;
    float vv[8];
    float mx = -INFINITY;
#pragma unroll
    for (int i = 0; i < 8; ++i) {
        float rc = (i & 1) ? bhi(pr[i >> 1]) : blo(pr[i >> 1]);
        int c = r * 8 + i;
        vv[i] = (c < 40) ? (a[i] * inv + rc) : -INFINITY;
        mx = fmaxf(mx, vv[i]);
    }
    mx = fmaxf(mx, __shfl_xor(mx, 1));
    mx = fmaxf(mx, __shfl_xor(mx, 2));
    mx = fmaxf(mx, __shfl_xor(mx, 4));
    float s = 0.f;
#pragma unroll
    for (int i = 0; i < 8; ++i) {
        int c = r * 8 + i;
        if (c < 40) s += __expf(vv[i] - mx);
    }
    s += __shfl_xor(s, 1);
    s += __shfl_xor(s, 2);
    s += __shfl_xor(s, 4);
    float lse = mx + __logf(s);
    if (g == 0 && r < 5) {
        float4 o0 = make_float4(vv[0] - lse, vv[1] - lse, vv[2] - lse, vv[3] - lse);
        float4 o1 = make_float4(vv[4] - lse, vv[5] - lse, vv[6] - lse, vv[7] - lse);
        *(float4*)(out + (size_t)node * 40 + r * 8)     = o0;
        *(float4*)(out + (size_t)node * 40 + r * 8 + 4) = o1;
    }
}

// ---------------------------------------------------------------- launch
extern "C" void kernel_launch(void* const* d_in, const int* in_sizes, int n_in,
                              void* d_out, int out_size, void* d_ws, size_t ws_size,
                              hipStream_t stream) {
    const float* x   = (const float*)d_in[0];
    const int*   ei  = (const int*)d_in[1];
    const float* Wl0 = (const float*)d_in[2];
    const float* Wr0 = (const float*)d_in[3];
    const float* b0  = (const float*)d_in[4];
    const float* Wl1 = (const float*)d_in[5];
    const float* Wr1 = (const float*)d_in[6];
    const float* b1  = (const float*)d_in[7];
    const float* Wl2 = (const float*)d_in[8];
    const float* Wr2 = (const float*)d_in[9];
    const float* b2  = (const float*)d_in[10];
    const int nN = in_sizes[0] / D;
    const int E  = in_sizes[1] / 2;
    const int* src = ei;
    const int* dst = ei + E;

    char* w = (char*)d_ws;
    auto alloc = [&](size_t bytes) { char* p = w; w += (bytes + 255) & ~(size_t)255; return p; };
    int*    deg    = (int*)   alloc((size_t)nN * 4);
    int*    rowptr = (int*)   alloc((size_t)(nN + 1) * 4);
    int*    bsum   = (int*)   alloc((size_t)((nN + 255) / 256) * 4);
    int*    col    = (int*)   alloc((size_t)E * 4);
    ushort* AbufA  = (ushort*)alloc((size_t)nN * 256 * 2);    // [agg | feat] bf16
    ushort* AbufB  = (ushort*)alloc((size_t)nN * 256 * 2);
    ushort* Wtg0   = (ushort*)alloc((size_t)128 * 256 * 2);
    ushort* Wtg1   = (ushort*)alloc((size_t)128 * 256 * 2);
    ushort* W2tg   = (ushort*)alloc((size_t)80 * 128 * 2);
    // pos aliases AbufB: dead after k_place2, first AbufB write is layer-0 GEMM
    int*    pos    = (int*)AbufB;
    // P/R alias into AbufB (dead after layer-1 GEMM reads it)
    ushort* Pbuf   = AbufB;                    // [N,40] bf16 packed
    ushort* Rbuf   = AbufB + (size_t)nN * 40;  // [N,40] bf16 (8MB offset, 128B-aligned)
    float*  logits = (float*)d_out;

    const int NB        = (nN + 255) / 256;
    const int GATH_BLKS = (nN + 7) / 8;        // 8 nodes per block (2 per wave)
    const int G40_BLKS  = (nN + 15) / 16;      // 16 nodes per block (4 per wave)
    const int GEMM_BLKS = (nN + 127) / 128;
    const int n4        = nN * 32;
    int prep_max = n4;                          // n4 > E and > prepw range here
    if (E > prep_max) prep_max = E;
    const int PREP_BLKS = (prep_max + 255) / 256;

    // ---- CSR build + casts + weight prep (fused prologue)
    hipMemsetAsync(deg, 0, (size_t)nN * 4, stream);
    k_prep  <<<PREP_BLKS, 256, 0, stream>>>(dst, deg, pos, E, x, AbufA, n4,
                                            Wl0, Wr0, Wl1, Wr1, Wl2, Wr2,
                                            Wtg0, Wtg1, W2tg);
    k_scan1 <<<NB, 256, 0, stream>>>(deg, rowptr, bsum, nN);
    k_scan2 <<<1, 512, 0, stream>>>(bsum, NB);
    k_scan3 <<<NB, 256, 0, stream>>>(rowptr, bsum, nN, E);
    k_place2<<<(E + 255) / 256, 256, 0, stream>>>(src, dst, rowptr, pos, col, E);

    // ---- layer 0
    k_gather128<<<GATH_BLKS, 256, 0, stream>>>(AbufA + 128, AbufA, rowptr, col, nN);
    k_gemm_mfma<128, 256, 264, 0><<<GEMM_BLKS, 256, 0, stream>>>(
        AbufA, 256, Wtg0, b0, AbufB + 128, 256, nullptr, nN);

    // ---- layer 1
    k_gather128<<<GATH_BLKS, 256, 0, stream>>>(AbufB + 128, AbufB, rowptr, col, nN);
    k_gemm_mfma<128, 256, 264, 0><<<GEMM_BLKS, 256, 0, stream>>>(
        AbufB, 256, Wtg1, b1, AbufA + 128, 256, nullptr, nN);   // h1 -> AbufA cols 128+

    // ---- layer 2: project first, then 40-dim gather + log_softmax
    k_gemm_mfma<80, 128, 136, 1><<<GEMM_BLKS, 256, 0, stream>>>(
        AbufA + 128, 256, W2tg, b2, Pbuf, 40, Rbuf, nN);
    k_gather40_lsm<<<G40_BLKS, 256, 0, stream>>>(Pbuf, Rbuf, rowptr, col, logits, nN);
}